// Round 9
// baseline (351.777 us; speedup 1.0000x reference)
//
#include <hip/hip_runtime.h>
#include <hip/hip_bf16.h>

#define N_NODES 50000
#define N_EDGES 1600000
#define IN_C 256
#define HID_C 256
#define OUT_C 10
#define CD_STRIDE 32
#define SLOT_CAP 96      // max degree; Poisson(32) max over 50K nodes ~60; 96 = 11 sigma
#define NBUCKET 196      // ceil(50000/256) dst-buckets of 256 nodes
#define EBUF_CAP 9216    // per-bucket edge capacity; mean 8163, sigma 90 -> +11.7 sigma
#define M_TILES 391      // (N_NODES+127)/128
#define NPASS 8          // 256 cols / 32 per pass; slab 3.2 MB < 4 MB XCD-L2

typedef short bf16x8 __attribute__((ext_vector_type(8)));
typedef float f32x4 __attribute__((ext_vector_type(4)));

static __device__ __forceinline__ float b2f(short v) {
    unsigned u = (unsigned)(unsigned short)v << 16;
    return __builtin_bit_cast(float, u);
}
static __device__ __forceinline__ short f2b(float f) {
    __hip_bfloat16 h = __float2bfloat16(f);
    return __builtin_bit_cast(short, h);
}
static __device__ __forceinline__ int4 pack8(float4 a, float4 b) {
    bf16x8 o;
    o[0] = f2b(a.x); o[1] = f2b(a.y); o[2] = f2b(a.z); o[3] = f2b(a.w);
    o[4] = f2b(b.x); o[5] = f2b(b.y); o[6] = f2b(b.z); o[7] = f2b(b.w);
    return __builtin_bit_cast(int4, o);
}

// ---------- phase A: partition edges into 196 dst-buckets (packed 4B records) ----------
__global__ __launch_bounds__(256) void k_part(const int* __restrict__ src,
                                              const int* __restrict__ dst,
                                              int* __restrict__ g_cursor,
                                              int* __restrict__ ebuf) {
    __shared__ int hist[NBUCKET];
    __shared__ int base[NBUCKET];
    __shared__ int pos[NBUCKET];
    int tid = threadIdx.x;
    if (tid < NBUCKET) { hist[tid] = 0; pos[tid] = 0; }
    __syncthreads();

    int4 s[4], d[4];
    bool valid[4];
#pragma unroll
    for (int q = 0; q < 4; ++q) {
        int idx = blockIdx.x * 1024 + q * 256 + tid;    // int4 index, 4 edges each
        valid[q] = (idx < N_EDGES / 4);
        if (valid[q]) {
            s[q] = ((const int4*)src)[idx];
            d[q] = ((const int4*)dst)[idx];
        }
    }
#pragma unroll
    for (int q = 0; q < 4; ++q) {
        if (valid[q]) {
            atomicAdd(&hist[d[q].x >> 8], 1);
            atomicAdd(&hist[d[q].y >> 8], 1);
            atomicAdd(&hist[d[q].z >> 8], 1);
            atomicAdd(&hist[d[q].w >> 8], 1);
        }
    }
    __syncthreads();
    if (tid < NBUCKET && hist[tid] > 0)
        base[tid] = atomicAdd(&g_cursor[tid], hist[tid]);
    __syncthreads();
#pragma unroll
    for (int q = 0; q < 4; ++q) {
        if (valid[q]) {
            int ss[4] = { s[q].x, s[q].y, s[q].z, s[q].w };
            int dd[4] = { d[q].x, d[q].y, d[q].z, d[q].w };
#pragma unroll
            for (int e = 0; e < 4; ++e) {
                int b = dd[e] >> 8;
                int p = base[b] + atomicAdd(&pos[b], 1);
                if (p < EBUF_CAP)
                    ebuf[b * EBUF_CAP + p] = ss[e] | ((dd[e] & 255) << 16);
            }
        }
    }
}

// ---------- phase B: one block per bucket, LDS counters, L2-local slot writes ----------
__global__ __launch_bounds__(256) void k_bucket(const int* __restrict__ ebuf,
                                                const int* __restrict__ g_cursor,
                                                int* __restrict__ cnt,
                                                unsigned short* __restrict__ slots) {
    __shared__ int lcnt[256];
    int b = blockIdx.x, tid = threadIdx.x;
    lcnt[tid] = 0;
    __syncthreads();
    int n_e = g_cursor[b];
    if (n_e > EBUF_CAP) n_e = EBUF_CAP;
    const int* eb = ebuf + b * EBUF_CAP;
    int n4 = n_e >> 2;
    for (int t = tid; t < n4; t += 256) {
        int4 v = ((const int4*)eb)[t];
        int vv[4] = { v.x, v.y, v.z, v.w };
#pragma unroll
        for (int e = 0; e < 4; ++e) {
            int dl = (vv[e] >> 16) & 255;
            int sv = vv[e] & 0xFFFF;
            int p = atomicAdd(&lcnt[dl], 1);
            if (p < SLOT_CAP) slots[(size_t)(b * 256 + dl) * SLOT_CAP + p] = (unsigned short)sv;
        }
    }
    for (int t = (n4 << 2) + tid; t < n_e; t += 256) {
        int vv = eb[t];
        int dl = (vv >> 16) & 255;
        int sv = vv & 0xFFFF;
        int p = atomicAdd(&lcnt[dl], 1);
        if (p < SLOT_CAP) slots[(size_t)(b * 256 + dl) * SLOT_CAP + p] = (unsigned short)sv;
    }
    __syncthreads();
    int nid = b * 256 + tid;
    if (nid < N_NODES) cnt[nid] = lcnt[tid];
}

// ---------- prep ----------
// Wt[n][k], n in [0,512): n<256 -> W1l[k][n], else W1r[k][n-256]
__global__ void k_prep_w(const float* __restrict__ W1l, const float* __restrict__ W1r,
                         __hip_bfloat16* __restrict__ Wt) {
    int idx = blockIdx.x * 256 + threadIdx.x;  // 512*256
    int n = idx >> 8, k = idx & 255;
    float v = (n < HID_C) ? W1l[k * HID_C + n] : W1r[k * HID_C + (n - HID_C)];
    Wt[idx] = __float2bfloat16(v);
}

// Wt2f rows 0..9 = W2l^T, rows 16..25 = W2r^T, fp32, stride 256
__global__ void k_prep_w2f(const float* __restrict__ W2l, const float* __restrict__ W2r,
                           float* __restrict__ Wt2f) {
    int idx = blockIdx.x * 256 + threadIdx.x;  // 20*256
    int r = idx >> 8, k = idx & 255;
    if (r < OUT_C) Wt2f[r * 256 + k] = W2l[k * OUT_C + r];
    else           Wt2f[(16 + r - OUT_C) * 256 + k] = W2r[k * OUT_C + (r - OUT_C)];
}

// ---------- GEMM1 (LDS-staged): [Ab2 | Bh] = X @ [W1l | W1r] (+b1 on Bh) ----------
// 128x128 tile, BK=64, 4 waves (2x2 of 64x64), reg-staged prefetch, LDS C epilogue,
// f32->bf16 fused into A-staging, XCD-aware flat-id swizzle (X panel L2-local).
// Left half writes the col-plane layout Ab2[pass][node][32] (pass = col>>5): each
// plane is a contiguous 3.2 MB slab that fits a 4 MB per-XCD L2 for k_aggc.
__global__ __launch_bounds__(256) void k_gemm1(
        const float* __restrict__ X, const __hip_bfloat16* __restrict__ Wt,
        const float* __restrict__ b1,
        __hip_bfloat16* __restrict__ Ab2, __hip_bfloat16* __restrict__ Bh) {
    __shared__ short Smem[2 * 128 * 64];   // As | Bs during K-loop; 128x128 C-tile after
    short* As = Smem;
    short* Bs = Smem + 128 * 64;
    int fid = blockIdx.x;
    int xcd = fid & 7, slot = fid >> 3;
    int m_t = (slot >> 2) * 8 + xcd;
    if (m_t >= M_TILES) return;            // block-uniform guard (1568 launched, 1564 live)
    int n_t = slot & 3;
    int m_base = m_t * 128;
    int n_base = n_t * 128;

    int tid = threadIdx.x;
    int wave = tid >> 6, lane = tid & 63;
    int r = lane & 15, quad = lane >> 4;
    int wr = wave >> 1, wc = wave & 1;

    // staging coords: thread covers 4 rows (q*32+srow) x 16B(bf16)/32B(f32) each
    int srow = tid >> 3;              // 0..31
    int kb8  = (tid & 7) * 16;        // byte offset in 128B bf16 row-slice
    int kelem = (tid & 7) * 8;        // element offset in 64-elem k-slice
    int swz  = kb8 ^ ((srow & 7) << 4);

    f32x4 acc[4][4];
#pragma unroll
    for (int i = 0; i < 4; ++i)
#pragma unroll
        for (int j = 0; j < 4; ++j) acc[i][j] = f32x4{0.f, 0.f, 0.f, 0.f};

    int4 av[4], bv[4];
    // prologue: load K-step 0 (A from f32 X, convert in regs; B already bf16)
#pragma unroll
    for (int q = 0; q < 4; ++q) {
        int grow = m_base + q * 32 + srow;
        if (grow > N_NODES - 1) grow = N_NODES - 1;
        const float* xp = X + (size_t)grow * IN_C + kelem;
        av[q] = pack8(*(const float4*)xp, *(const float4*)(xp + 4));
        int brow = n_base + q * 32 + srow;
        bv[q] = *(const int4*)((const char*)Wt + ((size_t)brow * 512 + kb8));
    }

    for (int kk = 0; kk < 4; ++kk) {
        if (kk) __syncthreads();                 // prior reads done before overwrite
#pragma unroll
        for (int q = 0; q < 4; ++q) {
            *(int4*)((char*)As + (size_t)((q * 32 + srow) * 128 + swz)) = av[q];
            *(int4*)((char*)Bs + (size_t)((q * 32 + srow) * 128 + swz)) = bv[q];
        }
        __syncthreads();

        if (kk < 3) {                            // prefetch next K-step during compute
            int ke = (kk + 1) * 64 + kelem;
            int kbyte = (kk + 1) * 128 + kb8;
#pragma unroll
            for (int q = 0; q < 4; ++q) {
                int grow = m_base + q * 32 + srow;
                if (grow > N_NODES - 1) grow = N_NODES - 1;
                const float* xp = X + (size_t)grow * IN_C + ke;
                av[q] = pack8(*(const float4*)xp, *(const float4*)(xp + 4));
                int brow = n_base + q * 32 + srow;
                bv[q] = *(const int4*)((const char*)Wt + ((size_t)brow * 512 + kbyte));
            }
        }

#pragma unroll
        for (int s = 0; s < 2; ++s) {
            int kfb = (s * 64 + quad * 16) ^ ((r & 7) << 4);
            bf16x8 a[4], b[4];
#pragma unroll
            for (int i = 0; i < 4; ++i)
                a[i] = *(const bf16x8*)((const char*)As + (size_t)((wr * 64 + i * 16 + r) * 128) + kfb);
#pragma unroll
            for (int j = 0; j < 4; ++j)
                b[j] = *(const bf16x8*)((const char*)Bs + (size_t)((wc * 64 + j * 16 + r) * 128) + kfb);
#pragma unroll
            for (int i = 0; i < 4; ++i)
#pragma unroll
                for (int j = 0; j < 4; ++j)
                    acc[i][j] = __builtin_amdgcn_mfma_f32_16x16x32_bf16(a[i], b[j], acc[i][j], 0, 0, 0);
        }
    }

    // ---- C epilogue via LDS: scatter acc (bf16) into 128x128 tile, then coalesced copy ----
    __syncthreads();                      // all waves done reading As/Bs
    short* Cs = Smem;                     // 128 rows x 128 cols bf16, 256B rows, swizzled
    bool left = (n_base < HID_C);         // block-uniform (n_t 0,1 -> Ab2; 2,3 -> Bh)
#pragma unroll
    for (int j = 0; j < 4; ++j) {
        int coll = wc * 64 + 16 * j + r;  // local col 0..127
        float bias = left ? 0.f : b1[n_base + coll - HID_C];
#pragma unroll
        for (int i = 0; i < 4; ++i) {
#pragma unroll
            for (int ii = 0; ii < 4; ++ii) {
                int rowl = wr * 64 + 16 * i + quad * 4 + ii;
                int byteoff = (coll * 2) ^ ((rowl & 7) << 4);   // 16B-granular XOR swizzle
                *(short*)((char*)Cs + rowl * 256 + byteoff) = f2b(acc[i][j][ii] + bias);
            }
        }
    }
    __syncthreads();

    // copy-out: 16 lanes cover one 256B row (16B each)
    int rrow = tid >> 4;                  // 0..15
    int cchunk = (tid & 15) * 16;         // byte offset in row
    for (int rb = 0; rb < 128; rb += 16) {
        int rowl = rb + rrow;
        int4 v = *(const int4*)((const char*)Cs + rowl * 256 + (cchunk ^ ((rowl & 7) << 4)));
        int grow = m_base + rowl;
        if (grow < N_NODES) {
            if (left) {
                int c0 = n_base + (cchunk >> 1);          // global col, multiple of 8
                // plane layout: Ab2[c0>>5][grow][c0&31]; 4-lane groups write 64B dense
                *(int4*)((char*)Ab2 + ((size_t)(c0 >> 5) * N_NODES + grow) * 64 + (c0 & 31) * 2) = v;
            } else {
                *(int4*)((char*)Bh + (size_t)grow * 512 + (size_t)((n_base - HID_C) * 2) + cchunk) = v;
            }
        }
    }
}

// ---------- layer1 mean-agg, col-split v2: 8 passes x 32 cols, 2 nodes/wave ----------
// Pass slab = contiguous 3.2 MB plane (L2-resident per XCD). 16B loads: total VMEM
// instruction count matches the flat kernel (51.2M) while past-L2 bytes drop ~2.5x.
// lane = h*32 + g*4 + c: h = node half, g = edge slot 0..7, c = 16B col-chunk 0..3.
__global__ __launch_bounds__(256) void k_aggc(
        const __hip_bfloat16* __restrict__ Ab2,
        const int* __restrict__ cnt,
        const unsigned short* __restrict__ slots,
        __hip_bfloat16* __restrict__ agg) {      // [NPASS][N_NODES][32] bf16 means
    int wave = threadIdx.x >> 6, lane = threadIdx.x & 63;
    int pass = blockIdx.y;
    int h = lane >> 5, g = (lane >> 2) & 7, c = lane & 3;
    int nid = blockIdx.x * 8 + wave * 2 + h;     // grid.x 6250 -> 50000 exact
    const unsigned short* row = slots + (size_t)nid * SLOT_CAP;
    int n = cnt[nid];
    if (n > SLOT_CAP) n = SLOT_CAP;

    const char* base = (const char*)Ab2 + (size_t)pass * N_NODES * 64 + c * 16;

    float a0 = 0.f, a1 = 0.f, a2 = 0.f, a3 = 0.f, a4 = 0.f, a5 = 0.f, a6 = 0.f, a7 = 0.f;
    int e = 0;
    for (; e + 16 <= n; e += 16) {               // 2 gathers/lane in flight
        unsigned s0 = row[e + g], s1 = row[e + 8 + g];
        int4 v0 = *(const int4*)(base + (size_t)(s0 * 64u));
        int4 v1 = *(const int4*)(base + (size_t)(s1 * 64u));
        bf16x8 b0 = __builtin_bit_cast(bf16x8, v0);
        bf16x8 b1v = __builtin_bit_cast(bf16x8, v1);
        a0 += b2f(b0[0]) + b2f(b1v[0]); a1 += b2f(b0[1]) + b2f(b1v[1]);
        a2 += b2f(b0[2]) + b2f(b1v[2]); a3 += b2f(b0[3]) + b2f(b1v[3]);
        a4 += b2f(b0[4]) + b2f(b1v[4]); a5 += b2f(b0[5]) + b2f(b1v[5]);
        a6 += b2f(b0[6]) + b2f(b1v[6]); a7 += b2f(b0[7]) + b2f(b1v[7]);
    }
    if (e + 8 <= n) {
        unsigned s0 = row[e + g];
        int4 v0 = *(const int4*)(base + (size_t)(s0 * 64u));
        bf16x8 b0 = __builtin_bit_cast(bf16x8, v0);
        a0 += b2f(b0[0]); a1 += b2f(b0[1]); a2 += b2f(b0[2]); a3 += b2f(b0[3]);
        a4 += b2f(b0[4]); a5 += b2f(b0[5]); a6 += b2f(b0[6]); a7 += b2f(b0[7]);
        e += 8;
    }
    if (e + g < n) {
        unsigned s0 = row[e + g];
        int4 v0 = *(const int4*)(base + (size_t)(s0 * 64u));
        bf16x8 b0 = __builtin_bit_cast(bf16x8, v0);
        a0 += b2f(b0[0]); a1 += b2f(b0[1]); a2 += b2f(b0[2]); a3 += b2f(b0[3]);
        a4 += b2f(b0[4]); a5 += b2f(b0[5]); a6 += b2f(b0[6]); a7 += b2f(b0[7]);
    }
    // reduce over g (bits 2..4 of lane) — stays within each 32-lane node half
#pragma unroll
    for (int off = 4; off <= 16; off <<= 1) {
        a0 += __shfl_xor(a0, off, 64); a1 += __shfl_xor(a1, off, 64);
        a2 += __shfl_xor(a2, off, 64); a3 += __shfl_xor(a3, off, 64);
        a4 += __shfl_xor(a4, off, 64); a5 += __shfl_xor(a5, off, 64);
        a6 += __shfl_xor(a6, off, 64); a7 += __shfl_xor(a7, off, 64);
    }
    if (g == 0) {
        float inv = 1.f / fmaxf((float)n, 1.f);
        bf16x8 o;
        o[0] = f2b(a0 * inv); o[1] = f2b(a1 * inv); o[2] = f2b(a2 * inv); o[3] = f2b(a3 * inv);
        o[4] = f2b(a4 * inv); o[5] = f2b(a5 * inv); o[6] = f2b(a6 * inv); o[7] = f2b(a7 * inv);
        *(int4*)((char*)agg + (size_t)pass * N_NODES * 64 + (size_t)nid * 64 + c * 16) =
            __builtin_bit_cast(int4, o);
    }
}

// ---------- epilogue: h = relu(mean + Bh); CD = [h@W2l | h@W2r + b2] ----------
__global__ __launch_bounds__(256) void k_epi(
        const __hip_bfloat16* __restrict__ agg, const __hip_bfloat16* __restrict__ Bh,
        const float* __restrict__ Wt2f, const float* __restrict__ b2,
        float* __restrict__ CD) {
    int wave = threadIdx.x >> 6, lane = threadIdx.x & 63;
    int nid = blockIdx.x * 4 + wave;             // grid 12500 -> exact
    int half = lane >> 5, sub = lane & 31;
    int c8 = sub * 8;                            // both halves cover cols 0..255

    // agg is [pass][node][32]: lane's 8 cols live in plane sub>>2 at offset (sub&3)*8
    bf16x8 mv = *(const bf16x8*)((const char*)agg +
                 ((size_t)(sub >> 2) * N_NODES + nid) * 64 + (sub & 3) * 16);
    bf16x8 bb = *(const bf16x8*)(Bh + (size_t)nid * HID_C + c8);
    float h[8];
#pragma unroll
    for (int j = 0; j < 8; ++j)
        h[j] = fmaxf(b2f(mv[j]) + b2f(bb[j]), 0.f);

    // 10 dot products with W2 (fp32), reduce over the 32 lanes of this half
    const float* wbase = Wt2f + (half ? 16 * 256 : 0);
    float acc[10];
#pragma unroll
    for (int j = 0; j < 10; ++j) {
        f32x4 w0 = *(const f32x4*)(wbase + j * 256 + c8);
        f32x4 w1 = *(const f32x4*)(wbase + j * 256 + c8 + 4);
        float a = h[0] * w0[0] + h[1] * w0[1] + h[2] * w0[2] + h[3] * w0[3]
                + h[4] * w1[0] + h[5] * w1[1] + h[6] * w1[2] + h[7] * w1[3];
#pragma unroll
        for (int off = 16; off > 0; off >>= 1)
            a += __shfl_down(a, off, 32);
        acc[j] = a;
    }
    if (sub == 0) {
        float* o = CD + (size_t)nid * CD_STRIDE + half * 16;
        if (half == 0) {
#pragma unroll
            for (int j = 0; j < 10; ++j) o[j] = acc[j];
            o[10] = 0.f; o[11] = 0.f;
        } else {
#pragma unroll
            for (int j = 0; j < 10; ++j) o[j] = acc[j] + b2[j];
        }
    }
}

// ---------- layer2 aggregation + log_softmax: two nodes per wave (32 lanes each) ----------
__global__ __launch_bounds__(256) void k_agg2(
        const float* __restrict__ CD, const int* __restrict__ cnt,
        const unsigned short* __restrict__ slots, float* __restrict__ out) {
    int wave = threadIdx.x >> 6, lane = threadIdx.x & 63;
    int half = lane >> 5, sub = lane & 31;
    int nid = blockIdx.x * 8 + wave * 2 + half;   // grid 6250 -> exact
    const unsigned short* row = slots + (size_t)nid * SLOT_CAP;
    int n = cnt[nid];
    if (n > SLOT_CAP) n = SLOT_CAP;
    float s[10];
#pragma unroll
    for (int j = 0; j < 10; ++j) s[j] = 0.f;
    for (int e = sub; e < n; e += 32) {
        const float* cr = CD + (size_t)row[e] * CD_STRIDE;
        f32x4 v0 = *(const f32x4*)cr;
        f32x4 v1 = *(const f32x4*)(cr + 4);
        f32x4 v2 = *(const f32x4*)(cr + 8);   // cols 8..11 (10,11 zeroed)
#pragma unroll
        for (int j = 0; j < 4; ++j) { s[j] += v0[j]; s[4 + j] += v1[j]; }
        s[8] += v2[0]; s[9] += v2[1];
    }
#pragma unroll
    for (int j = 0; j < 10; ++j)
#pragma unroll
        for (int off = 16; off > 0; off >>= 1)
            s[j] += __shfl_down(s[j], off, 32);
    if (sub == 0) {
        float inv = 1.f / fmaxf((float)n, 1.f);
        float z[10], mx = -1e30f;
#pragma unroll
        for (int j = 0; j < 10; ++j) {
            z[j] = s[j] * inv + CD[(size_t)nid * CD_STRIDE + 16 + j];
            mx = fmaxf(mx, z[j]);
        }
        float se = 0.f;
#pragma unroll
        for (int j = 0; j < 10; ++j) se += expf(z[j] - mx);
        float lse = logf(se) + mx;
#pragma unroll
        for (int j = 0; j < 10; ++j) out[(size_t)nid * OUT_C + j] = z[j] - lse;
    }
}

extern "C" void kernel_launch(void* const* d_in, const int* in_sizes, int n_in,
                              void* d_out, int out_size, void* d_ws, size_t ws_size,
                              hipStream_t stream) {
    const float* x   = (const float*)d_in[0];
    const int*   ei  = (const int*)d_in[1];
    const float* W1l = (const float*)d_in[2];
    const float* W1r = (const float*)d_in[3];
    const float* b1  = (const float*)d_in[4];
    const float* W2l = (const float*)d_in[5];
    const float* W2r = (const float*)d_in[6];
    const float* b2  = (const float*)d_in[7];
    float* out = (float*)d_out;
    const int* src = ei;
    const int* dst = ei + N_EDGES;

    char* w = (char*)d_ws;
    size_t off = 0;
    auto alloc = [&](size_t bytes) -> void* {
        void* p = w + off;
        off = (off + bytes + 255) & ~(size_t)255;
        return p;
    };
    __hip_bfloat16* Wt   = (__hip_bfloat16*)alloc((size_t)2 * HID_C * IN_C * 2);
    float*          Wt2f = (float*)alloc((size_t)32 * 256 * 4);
    __hip_bfloat16* Ab2  = (__hip_bfloat16*)alloc((size_t)N_NODES * HID_C * 2);
    __hip_bfloat16* Bh   = (__hip_bfloat16*)alloc((size_t)N_NODES * HID_C * 2);
    __hip_bfloat16* agg  = (__hip_bfloat16*)alloc((size_t)N_NODES * HID_C * 2);
    float* CD = (float*)alloc((size_t)N_NODES * CD_STRIDE * 4);
    int* cnt      = (int*)alloc((size_t)N_NODES * 4);
    unsigned short* slots = (unsigned short*)alloc((size_t)N_NODES * SLOT_CAP * 2);
    int* g_cursor = (int*)alloc((size_t)NBUCKET * 4);
    int* ebuf     = (int*)alloc((size_t)NBUCKET * EBUF_CAP * 4);

    (void)hipMemsetAsync(g_cursor, 0, (size_t)NBUCKET * 4, stream);

    k_part<<<(N_EDGES / 4 + 1023) / 1024, 256, 0, stream>>>(src, dst, g_cursor, ebuf);
    k_bucket<<<NBUCKET, 256, 0, stream>>>(ebuf, g_cursor, cnt, slots);

    k_prep_w<<<512, 256, 0, stream>>>(W1l, W1r, Wt);
    k_prep_w2f<<<20, 256, 0, stream>>>(W2l, W2r, Wt2f);

    k_gemm1<<<8 * 196, 256, 0, stream>>>(x, Wt, b1, Ab2, Bh);
    k_aggc<<<dim3(N_NODES / 8, NPASS), 256, 0, stream>>>(Ab2, cnt, slots, agg);
    k_epi<<<N_NODES / 4, 256, 0, stream>>>(agg, Bh, Wt2f, b2, CD);
    k_agg2<<<N_NODES / 8, 256, 0, stream>>>(CD, cnt, slots, out);
}

// Round 10
// 344.510 us; speedup vs baseline: 1.0211x; 1.0211x over previous
//
#include <hip/hip_runtime.h>
#include <hip/hip_bf16.h>

#define N_NODES 50000
#define N_EDGES 1600000
#define IN_C 256
#define HID_C 256
#define OUT_C 10
#define CD_STRIDE 32
#define SLOT_CAP 96      // max degree; Poisson(32) max over 50K nodes ~60; 96 = 11 sigma
#define NBUCKET 196      // ceil(50000/256) dst-buckets of 256 nodes
#define EBUF_CAP 9216    // per-bucket edge capacity; mean 8163, sigma 90 -> +11.7 sigma

typedef short bf16x8 __attribute__((ext_vector_type(8)));
typedef float f32x4 __attribute__((ext_vector_type(4)));

static __device__ __forceinline__ float b2f(short v) {
    unsigned u = (unsigned)(unsigned short)v << 16;
    return __builtin_bit_cast(float, u);
}
static __device__ __forceinline__ short f2b(float f) {
    __hip_bfloat16 h = __float2bfloat16(f);
    return __builtin_bit_cast(short, h);
}
static __device__ __forceinline__ bf16x8 pack8(float4 a, float4 b) {
    bf16x8 o;
    o[0] = f2b(a.x); o[1] = f2b(a.y); o[2] = f2b(a.z); o[3] = f2b(a.w);
    o[4] = f2b(b.x); o[5] = f2b(b.y); o[6] = f2b(b.z); o[7] = f2b(b.w);
    return o;
}

// ---------- phase A: partition edges into 196 dst-buckets (packed 4B records) ----------
__global__ __launch_bounds__(256) void k_part(const int* __restrict__ src,
                                              const int* __restrict__ dst,
                                              int* __restrict__ g_cursor,
                                              int* __restrict__ ebuf) {
    __shared__ int hist[NBUCKET];
    __shared__ int base[NBUCKET];
    __shared__ int pos[NBUCKET];
    int tid = threadIdx.x;
    if (tid < NBUCKET) { hist[tid] = 0; pos[tid] = 0; }
    __syncthreads();

    int4 s[4], d[4];
    bool valid[4];
#pragma unroll
    for (int q = 0; q < 4; ++q) {
        int idx = blockIdx.x * 1024 + q * 256 + tid;    // int4 index, 4 edges each
        valid[q] = (idx < N_EDGES / 4);
        if (valid[q]) {
            s[q] = ((const int4*)src)[idx];
            d[q] = ((const int4*)dst)[idx];
        }
    }
#pragma unroll
    for (int q = 0; q < 4; ++q) {
        if (valid[q]) {
            atomicAdd(&hist[d[q].x >> 8], 1);
            atomicAdd(&hist[d[q].y >> 8], 1);
            atomicAdd(&hist[d[q].z >> 8], 1);
            atomicAdd(&hist[d[q].w >> 8], 1);
        }
    }
    __syncthreads();
    if (tid < NBUCKET && hist[tid] > 0)
        base[tid] = atomicAdd(&g_cursor[tid], hist[tid]);
    __syncthreads();
#pragma unroll
    for (int q = 0; q < 4; ++q) {
        if (valid[q]) {
            int ss[4] = { s[q].x, s[q].y, s[q].z, s[q].w };
            int dd[4] = { d[q].x, d[q].y, d[q].z, d[q].w };
#pragma unroll
            for (int e = 0; e < 4; ++e) {
                int b = dd[e] >> 8;
                int p = base[b] + atomicAdd(&pos[b], 1);
                if (p < EBUF_CAP)
                    ebuf[b * EBUF_CAP + p] = ss[e] | ((dd[e] & 255) << 16);
            }
        }
    }
}

// ---------- phase B: one 512-thread block per bucket (196 blocks was 0.77/CU) ----------
__global__ __launch_bounds__(512) void k_bucket(const int* __restrict__ ebuf,
                                                const int* __restrict__ g_cursor,
                                                int* __restrict__ cnt,
                                                unsigned short* __restrict__ slots) {
    __shared__ int lcnt[256];
    int b = blockIdx.x, tid = threadIdx.x;
    if (tid < 256) lcnt[tid] = 0;
    __syncthreads();
    int n_e = g_cursor[b];
    if (n_e > EBUF_CAP) n_e = EBUF_CAP;
    const int* eb = ebuf + b * EBUF_CAP;
    int n4 = n_e >> 2;
    for (int t = tid; t < n4; t += 512) {
        int4 v = ((const int4*)eb)[t];
        int vv[4] = { v.x, v.y, v.z, v.w };
#pragma unroll
        for (int e = 0; e < 4; ++e) {
            int dl = (vv[e] >> 16) & 255;
            int sv = vv[e] & 0xFFFF;
            int p = atomicAdd(&lcnt[dl], 1);
            if (p < SLOT_CAP) slots[(size_t)(b * 256 + dl) * SLOT_CAP + p] = (unsigned short)sv;
        }
    }
    for (int t = (n4 << 2) + tid; t < n_e; t += 512) {
        int vv = eb[t];
        int dl = (vv >> 16) & 255;
        int sv = vv & 0xFFFF;
        int p = atomicAdd(&lcnt[dl], 1);
        if (p < SLOT_CAP) slots[(size_t)(b * 256 + dl) * SLOT_CAP + p] = (unsigned short)sv;
    }
    __syncthreads();
    if (tid < 256) {
        int nid = b * 256 + tid;
        if (nid < N_NODES) cnt[nid] = lcnt[tid];
    }
}

// ---------- prep (merged): Wt[n][k] bf16 (512 blocks) + Wt2f fp32 (20 blocks) ----------
__global__ void k_prep(const float* __restrict__ W1l, const float* __restrict__ W1r,
                       const float* __restrict__ W2l, const float* __restrict__ W2r,
                       __hip_bfloat16* __restrict__ Wt, float* __restrict__ Wt2f) {
    int bid = blockIdx.x;
    if (bid < 512) {
        int idx = bid * 256 + threadIdx.x;  // 512*256
        int n = idx >> 8, k = idx & 255;
        float v = (n < HID_C) ? W1l[k * HID_C + n] : W1r[k * HID_C + (n - HID_C)];
        Wt[idx] = __float2bfloat16(v);
    } else {
        int idx = (bid - 512) * 256 + threadIdx.x;  // 20*256
        int r = idx >> 8, k = idx & 255;
        if (r < OUT_C) Wt2f[r * 256 + k] = W2l[k * OUT_C + r];
        else           Wt2f[(16 + r - OUT_C) * 256 + k] = W2r[k * OUT_C + (r - OUT_C)];
    }
}

// ---------- GEMM1 (barrier-free): [Ab | Bh] = X @ [W1l | W1r] (+b1 on Bh) ----------
// One independent wave per 64x64 output tile (6272 waves, 1568 blocks x 4). No LDS
// staging of A/B: B (0.26 MB) is permanently L2-resident; A is read straight from f32 X
// (one frag-load instr = 16 rows x 128B aligned window = line-perfect) and converted in
// regs. No __syncthreads anywhere -> compiler schedules loads across MFMAs freely.
// C goes through a wave-private 8KB LDS tile, written out as full 128B lines.
// XCD swizzle: the 8 n-tiles of an m-panel land on one XCD (fid = slot*8 + xcd).
__global__ __launch_bounds__(256) void k_gemm1(
        const float* __restrict__ X, const __hip_bfloat16* __restrict__ Wt,
        const float* __restrict__ b1,
        __hip_bfloat16* __restrict__ Ab, __hip_bfloat16* __restrict__ Bh) {
    __shared__ short Cs4[4][64 * 64];      // per-wave C tile, 8 KB each
    int fid = blockIdx.x;
    int xcd = fid & 7, slot = fid >> 3;    // slot 0..195
    int wave = threadIdx.x >> 6, lane = threadIdx.x & 63;
    int m_t = (slot >> 1) * 8 + xcd;       // 0..783 (784 m-tiles, last 2 dead)
    int n_t = (slot & 1) * 4 + wave;       // 0..7
    int m_base = m_t * 64;
    int n_base = n_t * 64;
    if (m_base >= N_NODES) return;         // wave-uniform; no barriers in kernel

    int r = lane & 15, quad = lane >> 4;

    f32x4 acc[4][4];
#pragma unroll
    for (int i = 0; i < 4; ++i)
#pragma unroll
        for (int j = 0; j < 4; ++j) acc[i][j] = f32x4{0.f, 0.f, 0.f, 0.f};

    const float* ap[4];
    const bf16x8* bp[4];
#pragma unroll
    for (int i = 0; i < 4; ++i) {
        int row = m_base + 16 * i + r;
        if (row > N_NODES - 1) row = N_NODES - 1;
        ap[i] = X + (size_t)row * IN_C + quad * 8;
        bp[i] = (const bf16x8*)(Wt + (size_t)(n_base + 16 * i + r) * IN_C + quad * 8);
    }

#pragma unroll
    for (int kk = 0; kk < 8; ++kk) {       // K-step = 32
        bf16x8 b[4];
#pragma unroll
        for (int j = 0; j < 4; ++j) b[j] = bp[j][kk * 4];
#pragma unroll
        for (int i = 0; i < 4; ++i) {
            float4 lo = *(const float4*)(ap[i] + kk * 32);
            float4 hi = *(const float4*)(ap[i] + kk * 32 + 4);
            bf16x8 a = pack8(lo, hi);
#pragma unroll
            for (int j = 0; j < 4; ++j)
                acc[i][j] = __builtin_amdgcn_mfma_f32_16x16x32_bf16(a, b[j], acc[i][j], 0, 0, 0);
        }
    }

    // ---- C epilogue via wave-private LDS tile (64x64 bf16, 128B rows, swizzled) ----
    short* cs = Cs4[wave];
    bool left = (n_base < HID_C);          // wave-uniform
#pragma unroll
    for (int j = 0; j < 4; ++j) {
        int coll = 16 * j + r;             // local col 0..63
        float bias = left ? 0.f : b1[n_base + coll - HID_C];
#pragma unroll
        for (int i = 0; i < 4; ++i) {
#pragma unroll
            for (int ii = 0; ii < 4; ++ii) {
                int rowl = 16 * i + quad * 4 + ii;
                int byteoff = (coll * 2) ^ ((rowl & 7) << 4);   // 16B-granular XOR swizzle
                *(short*)((char*)cs + rowl * 128 + byteoff) = f2b(acc[i][j][ii] + bias);
            }
        }
    }
    // same wave reads its own region: in-wave lgkmcnt ordering, no barrier needed

    // copy-out: 8 lanes cover one 128B row (16B each) -> exactly one HBM line per row
    int rg = lane >> 3;                    // 0..7
    int chunk = (lane & 7) * 16;           // byte offset in 128B row
    size_t colbyte = left ? (size_t)(n_base * 2) : (size_t)((n_base - HID_C) * 2);
    char* outp = left ? (char*)Ab : (char*)Bh;
#pragma unroll
    for (int rb = 0; rb < 64; rb += 8) {
        int rowl = rb + rg;
        int4 v = *(const int4*)((const char*)cs + rowl * 128 + (chunk ^ ((rowl & 7) << 4)));
        int grow = m_base + rowl;
        if (grow < N_NODES)
            *(int4*)(outp + (size_t)grow * 512 + colbyte + chunk) = v;
    }
}

// ---------- fused: layer1 mean-agg + relu + GEMM2 epilogue -> CD (R0-proven 119 us) ----
__global__ __launch_bounds__(256) void k_agg1f(
        const __hip_bfloat16* __restrict__ Ab, const __hip_bfloat16* __restrict__ Bh,
        const int* __restrict__ cnt, const unsigned short* __restrict__ slots,
        const float* __restrict__ Wt2f, const float* __restrict__ b2,
        float* __restrict__ CD) {
    int wave = threadIdx.x >> 6, lane = threadIdx.x & 63;
    int nid = blockIdx.x * 4 + wave;          // grid 12500 -> exact
    int half = lane >> 5;
    int c8 = (lane & 31) * 8;
    const unsigned short* row = slots + (size_t)nid * SLOT_CAP;
    int n = cnt[nid];
    if (n > SLOT_CAP) n = SLOT_CAP;
    int mid = (n + 1) >> 1;
    int beg = half ? mid : 0;
    int end = half ? n : mid;

    float s0[8], s1[8], s2[8], s3[8];
#pragma unroll
    for (int j = 0; j < 8; ++j) { s0[j] = 0.f; s1[j] = 0.f; s2[j] = 0.f; s3[j] = 0.f; }

    const __hip_bfloat16* abc = Ab + c8;
    int e = beg;
    for (; e + 4 <= end; e += 4) {
        int i0 = row[e], i1 = row[e + 1], i2 = row[e + 2], i3 = row[e + 3];
        bf16x8 v0 = *(const bf16x8*)(abc + (size_t)i0 * HID_C);
        bf16x8 v1 = *(const bf16x8*)(abc + (size_t)i1 * HID_C);
        bf16x8 v2 = *(const bf16x8*)(abc + (size_t)i2 * HID_C);
        bf16x8 v3 = *(const bf16x8*)(abc + (size_t)i3 * HID_C);
#pragma unroll
        for (int j = 0; j < 8; ++j) {
            s0[j] += b2f(v0[j]); s1[j] += b2f(v1[j]);
            s2[j] += b2f(v2[j]); s3[j] += b2f(v3[j]);
        }
    }
    for (; e < end; ++e) {
        int i0 = row[e];
        bf16x8 v0 = *(const bf16x8*)(abc + (size_t)i0 * HID_C);
#pragma unroll
        for (int j = 0; j < 8; ++j) s0[j] += b2f(v0[j]);
    }
#pragma unroll
    for (int j = 0; j < 8; ++j) s0[j] += (s1[j] + s2[j]) + s3[j];
#pragma unroll
    for (int j = 0; j < 8; ++j) s0[j] += __shfl_down(s0[j], 32, 64);

    // h = relu(mean + Bh) computed on half0, broadcast to half1
    float h[8];
    float inv = 1.f / fmaxf((float)n, 1.f);
    if (half == 0) {
        bf16x8 bb = *(const bf16x8*)(Bh + (size_t)nid * HID_C + c8);
#pragma unroll
        for (int j = 0; j < 8; ++j)
            h[j] = fmaxf(s0[j] * inv + b2f(bb[j]), 0.f);
    }
#pragma unroll
    for (int j = 0; j < 8; ++j) h[j] = __shfl(h[j], lane & 31, 64);

    // 10 dot products with W2 (fp32), reduce over 32 lanes of this half
    const float* wbase = Wt2f + (half ? 16 * 256 : 0);
    float acc[10];
#pragma unroll
    for (int j = 0; j < 10; ++j) {
        f32x4 w0 = *(const f32x4*)(wbase + j * 256 + c8);
        f32x4 w1 = *(const f32x4*)(wbase + j * 256 + c8 + 4);
        float a = h[0] * w0[0] + h[1] * w0[1] + h[2] * w0[2] + h[3] * w0[3]
                + h[4] * w1[0] + h[5] * w1[1] + h[6] * w1[2] + h[7] * w1[3];
#pragma unroll
        for (int off = 16; off > 0; off >>= 1)
            a += __shfl_down(a, off, 32);
        acc[j] = a;
    }
    if ((lane & 31) == 0) {
        float* o = CD + (size_t)nid * CD_STRIDE + half * 16;
        if (half == 0) {
#pragma unroll
            for (int j = 0; j < 10; ++j) o[j] = acc[j];
            o[10] = 0.f; o[11] = 0.f;
        } else {
#pragma unroll
            for (int j = 0; j < 10; ++j) o[j] = acc[j] + b2[j];
        }
    }
}

// ---------- layer2 aggregation + log_softmax: two nodes per wave (32 lanes each) ----------
__global__ __launch_bounds__(256) void k_agg2(
        const float* __restrict__ CD, const int* __restrict__ cnt,
        const unsigned short* __restrict__ slots, float* __restrict__ out) {
    int wave = threadIdx.x >> 6, lane = threadIdx.x & 63;
    int half = lane >> 5, sub = lane & 31;
    int nid = blockIdx.x * 8 + wave * 2 + half;   // grid 6250 -> exact
    const unsigned short* row = slots + (size_t)nid * SLOT_CAP;
    int n = cnt[nid];
    if (n > SLOT_CAP) n = SLOT_CAP;
    float s[10];
#pragma unroll
    for (int j = 0; j < 10; ++j) s[j] = 0.f;
    for (int e = sub; e < n; e += 32) {
        const float* cr = CD + (size_t)row[e] * CD_STRIDE;
        f32x4 v0 = *(const f32x4*)cr;
        f32x4 v1 = *(const f32x4*)(cr + 4);
        f32x4 v2 = *(const f32x4*)(cr + 8);   // cols 8..11 (10,11 zeroed)
#pragma unroll
        for (int j = 0; j < 4; ++j) { s[j] += v0[j]; s[4 + j] += v1[j]; }
        s[8] += v2[0]; s[9] += v2[1];
    }
#pragma unroll
    for (int j = 0; j < 10; ++j)
#pragma unroll
        for (int off = 16; off > 0; off >>= 1)
            s[j] += __shfl_down(s[j], off, 32);
    if (sub == 0) {
        float inv = 1.f / fmaxf((float)n, 1.f);
        float z[10], mx = -1e30f;
#pragma unroll
        for (int j = 0; j < 10; ++j) {
            z[j] = s[j] * inv + CD[(size_t)nid * CD_STRIDE + 16 + j];
            mx = fmaxf(mx, z[j]);
        }
        float se = 0.f;
#pragma unroll
        for (int j = 0; j < 10; ++j) se += expf(z[j] - mx);
        float lse = logf(se) + mx;
#pragma unroll
        for (int j = 0; j < 10; ++j) out[(size_t)nid * OUT_C + j] = z[j] - lse;
    }
}

extern "C" void kernel_launch(void* const* d_in, const int* in_sizes, int n_in,
                              void* d_out, int out_size, void* d_ws, size_t ws_size,
                              hipStream_t stream) {
    const float* x   = (const float*)d_in[0];
    const int*   ei  = (const int*)d_in[1];
    const float* W1l = (const float*)d_in[2];
    const float* W1r = (const float*)d_in[3];
    const float* b1  = (const float*)d_in[4];
    const float* W2l = (const float*)d_in[5];
    const float* W2r = (const float*)d_in[6];
    const float* b2  = (const float*)d_in[7];
    float* out = (float*)d_out;
    const int* src = ei;
    const int* dst = ei + N_EDGES;

    char* w = (char*)d_ws;
    size_t off = 0;
    auto alloc = [&](size_t bytes) -> void* {
        void* p = w + off;
        off = (off + bytes + 255) & ~(size_t)255;
        return p;
    };
    __hip_bfloat16* Wt   = (__hip_bfloat16*)alloc((size_t)2 * HID_C * IN_C * 2);
    float*          Wt2f = (float*)alloc((size_t)32 * 256 * 4);
    __hip_bfloat16* Ab   = (__hip_bfloat16*)alloc((size_t)N_NODES * HID_C * 2);
    __hip_bfloat16* Bh   = (__hip_bfloat16*)alloc((size_t)N_NODES * HID_C * 2);
    float* CD = (float*)alloc((size_t)N_NODES * CD_STRIDE * 4);
    int* cnt      = (int*)alloc((size_t)N_NODES * 4);
    unsigned short* slots = (unsigned short*)alloc((size_t)N_NODES * SLOT_CAP * 2);
    int* g_cursor = (int*)alloc((size_t)NBUCKET * 4);
    int* ebuf     = (int*)alloc((size_t)NBUCKET * EBUF_CAP * 4);

    (void)hipMemsetAsync(g_cursor, 0, (size_t)NBUCKET * 4, stream);

    k_part<<<(N_EDGES / 4 + 1023) / 1024, 256, 0, stream>>>(src, dst, g_cursor, ebuf);
    k_bucket<<<NBUCKET, 512, 0, stream>>>(ebuf, g_cursor, cnt, slots);

    k_prep<<<532, 256, 0, stream>>>(W1l, W1r, W2l, W2r, Wt, Wt2f);

    k_gemm1<<<8 * 196, 256, 0, stream>>>(x, Wt, b1, Ab, Bh);
    k_agg1f<<<N_NODES / 4, 256, 0, stream>>>(Ab, Bh, cnt, slots, Wt2f, b2, CD);
    k_agg2<<<N_NODES / 8, 256, 0, stream>>>(CD, cnt, slots, out);
}

// Round 11
// 315.953 us; speedup vs baseline: 1.1134x; 1.0904x over previous
//
#include <hip/hip_runtime.h>
#include <hip/hip_bf16.h>

#define N_NODES 50000
#define N_EDGES 1600000
#define IN_C 256
#define HID_C 256
#define OUT_C 10
#define CD_STRIDE 32
#define SLOT_CAP 96      // max degree; Poisson(32) max over 50K nodes ~60; 96 = 11 sigma
#define NBUCKET 196      // ceil(50000/256) dst-buckets of 256 nodes
#define EBUF_CAP 9216    // per-bucket edge capacity; mean 8163, sigma 90 -> +11.7 sigma
#define M_TILES 391      // (N_NODES+127)/128
#define PART_BLOCKS 391  // ceil((N_EDGES/4)/1024)

typedef short bf16x8 __attribute__((ext_vector_type(8)));
typedef float f32x4 __attribute__((ext_vector_type(4)));

static __device__ __forceinline__ float b2f(short v) {
    unsigned u = (unsigned)(unsigned short)v << 16;
    return __builtin_bit_cast(float, u);
}
static __device__ __forceinline__ short f2b(float f) {
    __hip_bfloat16 h = __float2bfloat16(f);
    return __builtin_bit_cast(short, h);
}
static __device__ __forceinline__ int4 pack8i(float4 a, float4 b) {
    bf16x8 o;
    o[0] = f2b(a.x); o[1] = f2b(a.y); o[2] = f2b(a.z); o[3] = f2b(a.w);
    o[4] = f2b(b.x); o[5] = f2b(b.y); o[6] = f2b(b.z); o[7] = f2b(b.w);
    return __builtin_bit_cast(int4, o);
}

// ---------- prep (merged): Wt[n][k] bf16 (512 blocks) + Wt2f fp32 (20 blocks) ----------
__global__ void k_prep(const float* __restrict__ W1l, const float* __restrict__ W1r,
                       const float* __restrict__ W2l, const float* __restrict__ W2r,
                       __hip_bfloat16* __restrict__ Wt, float* __restrict__ Wt2f) {
    int bid = blockIdx.x;
    if (bid < 512) {
        int idx = bid * 256 + threadIdx.x;  // 512*256
        int n = idx >> 8, k = idx & 255;
        float v = (n < HID_C) ? W1l[k * HID_C + n] : W1r[k * HID_C + (n - HID_C)];
        Wt[idx] = __float2bfloat16(v);
    } else {
        int idx = (bid - 512) * 256 + threadIdx.x;  // 20*256
        int r = idx >> 8, k = idx & 255;
        if (r < OUT_C) Wt2f[r * 256 + k] = W2l[k * OUT_C + r];
        else           Wt2f[(16 + r - OUT_C) * 256 + k] = W2r[k * OUT_C + (r - OUT_C)];
    }
}

// ---------- fused launch: blocks 0..390 = edge partition; 391..1958 = GEMM1 ----------
// The two chains {part} and {gemm1} are independent (disjoint in/out); fusing them into
// one launch overlaps part's ~15-25 us under gemm1's latency slack (R5: gemm1 occ 20%).
// GEMM1 (R7-proven): 128x128 tile, BK=64, 4 waves (2x2 of 64x64), reg-staged prefetch,
// f32->bf16 fused into A-staging, XCD-aware flat-id swizzle, LDS C epilogue.
__global__ __launch_bounds__(256) void k_gp(
        const int* __restrict__ src, const int* __restrict__ dst,
        int* __restrict__ g_cursor, int* __restrict__ ebuf,
        const float* __restrict__ X, const __hip_bfloat16* __restrict__ Wt,
        const float* __restrict__ b1,
        __hip_bfloat16* __restrict__ Ab, __hip_bfloat16* __restrict__ Bh) {
    __shared__ short Smem[2 * 128 * 64];   // gemm: As|Bs then C-tile; part: 3KB counters
    int tid = threadIdx.x;

    if (blockIdx.x < PART_BLOCKS) {
        // ================= edge-partition path =================
        int* hist = (int*)Smem;            // [256] (196 used)
        int* base = hist + 256;
        int* pos  = base + 256;
        if (tid < NBUCKET) { hist[tid] = 0; pos[tid] = 0; }
        __syncthreads();

        int4 s[4], d[4];
        bool valid[4];
#pragma unroll
        for (int q = 0; q < 4; ++q) {
            int idx = blockIdx.x * 1024 + q * 256 + tid;    // int4 index, 4 edges each
            valid[q] = (idx < N_EDGES / 4);
            if (valid[q]) {
                s[q] = ((const int4*)src)[idx];
                d[q] = ((const int4*)dst)[idx];
            }
        }
#pragma unroll
        for (int q = 0; q < 4; ++q) {
            if (valid[q]) {
                atomicAdd(&hist[d[q].x >> 8], 1);
                atomicAdd(&hist[d[q].y >> 8], 1);
                atomicAdd(&hist[d[q].z >> 8], 1);
                atomicAdd(&hist[d[q].w >> 8], 1);
            }
        }
        __syncthreads();
        if (tid < NBUCKET && hist[tid] > 0)
            base[tid] = atomicAdd(&g_cursor[tid], hist[tid]);
        __syncthreads();
#pragma unroll
        for (int q = 0; q < 4; ++q) {
            if (valid[q]) {
                int ss[4] = { s[q].x, s[q].y, s[q].z, s[q].w };
                int dd[4] = { d[q].x, d[q].y, d[q].z, d[q].w };
#pragma unroll
                for (int e = 0; e < 4; ++e) {
                    int b = dd[e] >> 8;
                    int p = base[b] + atomicAdd(&pos[b], 1);
                    if (p < EBUF_CAP)
                        ebuf[b * EBUF_CAP + p] = ss[e] | ((dd[e] & 255) << 16);
                }
            }
        }
        return;
    }

    // ================= GEMM1 path =================
    short* As = Smem;
    short* Bs = Smem + 128 * 64;
    int fid = blockIdx.x - PART_BLOCKS;
    int xcd = fid & 7, slot = fid >> 3;
    int m_t = (slot >> 2) * 8 + xcd;
    if (m_t >= M_TILES) return;            // block-uniform guard
    int n_t = slot & 3;
    int m_base = m_t * 128;
    int n_base = n_t * 128;

    int wave = tid >> 6, lane = tid & 63;
    int r = lane & 15, quad = lane >> 4;
    int wr = wave >> 1, wc = wave & 1;

    // staging coords: thread covers 4 rows (q*32+srow) x 16B(bf16)/32B(f32) each
    int srow = tid >> 3;              // 0..31
    int kb8  = (tid & 7) * 16;        // byte offset in 128B bf16 row-slice
    int kelem = (tid & 7) * 8;        // element offset in 64-elem k-slice
    int swz  = kb8 ^ ((srow & 7) << 4);

    f32x4 acc[4][4];
#pragma unroll
    for (int i = 0; i < 4; ++i)
#pragma unroll
        for (int j = 0; j < 4; ++j) acc[i][j] = f32x4{0.f, 0.f, 0.f, 0.f};

    int4 av[4], bv[4];
    // prologue: load K-step 0 (A from f32 X, convert in regs; B already bf16)
#pragma unroll
    for (int q = 0; q < 4; ++q) {
        int grow = m_base + q * 32 + srow;
        if (grow > N_NODES - 1) grow = N_NODES - 1;
        const float* xp = X + (size_t)grow * IN_C + kelem;
        av[q] = pack8i(*(const float4*)xp, *(const float4*)(xp + 4));
        int brow = n_base + q * 32 + srow;
        bv[q] = *(const int4*)((const char*)Wt + ((size_t)brow * 512 + kb8));
    }

    for (int kk = 0; kk < 4; ++kk) {
        if (kk) __syncthreads();                 // prior reads done before overwrite
#pragma unroll
        for (int q = 0; q < 4; ++q) {
            *(int4*)((char*)As + (size_t)((q * 32 + srow) * 128 + swz)) = av[q];
            *(int4*)((char*)Bs + (size_t)((q * 32 + srow) * 128 + swz)) = bv[q];
        }
        __syncthreads();

        if (kk < 3) {                            // prefetch next K-step during compute
            int ke = (kk + 1) * 64 + kelem;
            int kbyte = (kk + 1) * 128 + kb8;
#pragma unroll
            for (int q = 0; q < 4; ++q) {
                int grow = m_base + q * 32 + srow;
                if (grow > N_NODES - 1) grow = N_NODES - 1;
                const float* xp = X + (size_t)grow * IN_C + ke;
                av[q] = pack8i(*(const float4*)xp, *(const float4*)(xp + 4));
                int brow = n_base + q * 32 + srow;
                bv[q] = *(const int4*)((const char*)Wt + ((size_t)brow * 512 + kbyte));
            }
        }

#pragma unroll
        for (int s = 0; s < 2; ++s) {
            int kfb = (s * 64 + quad * 16) ^ ((r & 7) << 4);
            bf16x8 a[4], b[4];
#pragma unroll
            for (int i = 0; i < 4; ++i)
                a[i] = *(const bf16x8*)((const char*)As + (size_t)((wr * 64 + i * 16 + r) * 128) + kfb);
#pragma unroll
            for (int j = 0; j < 4; ++j)
                b[j] = *(const bf16x8*)((const char*)Bs + (size_t)((wc * 64 + j * 16 + r) * 128) + kfb);
#pragma unroll
            for (int i = 0; i < 4; ++i)
#pragma unroll
                for (int j = 0; j < 4; ++j)
                    acc[i][j] = __builtin_amdgcn_mfma_f32_16x16x32_bf16(a[i], b[j], acc[i][j], 0, 0, 0);
        }
    }

    // ---- C epilogue via LDS: scatter acc (bf16) into 128x128 tile, then coalesced copy ----
    __syncthreads();                      // all waves done reading As/Bs
    short* Cs = Smem;                     // 128 rows x 128 cols bf16, 256B rows, swizzled
    bool left = (n_base < HID_C);         // block-uniform (n_t 0,1 -> Ab; 2,3 -> Bh)
#pragma unroll
    for (int j = 0; j < 4; ++j) {
        int coll = wc * 64 + 16 * j + r;  // local col 0..127
        float bias = left ? 0.f : b1[n_base + coll - HID_C];
#pragma unroll
        for (int i = 0; i < 4; ++i) {
#pragma unroll
            for (int ii = 0; ii < 4; ++ii) {
                int rowl = wr * 64 + 16 * i + quad * 4 + ii;
                int byteoff = (coll * 2) ^ ((rowl & 7) << 4);   // 16B-granular XOR swizzle
                *(short*)((char*)Cs + rowl * 256 + byteoff) = f2b(acc[i][j][ii] + bias);
            }
        }
    }
    __syncthreads();

    // copy-out: 16 lanes cover one 256B row (16B each) -> fully-coalesced lines
    int rrow = tid >> 4;                  // 0..15
    int cchunk = (tid & 15) * 16;         // byte offset in row
    size_t colbyte = left ? (size_t)(n_base * 2) : (size_t)((n_base - HID_C) * 2);
    char* outp = left ? (char*)Ab : (char*)Bh;
    for (int rb = 0; rb < 128; rb += 16) {
        int rowl = rb + rrow;
        int4 v = *(const int4*)((const char*)Cs + rowl * 256 + (cchunk ^ ((rowl & 7) << 4)));
        int grow = m_base + rowl;
        if (grow < N_NODES)
            *(int4*)(outp + (size_t)grow * 512 + colbyte + cchunk) = v;
    }
}

// ---------- phase B: one 512-thread block per bucket ----------
__global__ __launch_bounds__(512) void k_bucket(const int* __restrict__ ebuf,
                                                const int* __restrict__ g_cursor,
                                                int* __restrict__ cnt,
                                                unsigned short* __restrict__ slots) {
    __shared__ int lcnt[256];
    int b = blockIdx.x, tid = threadIdx.x;
    if (tid < 256) lcnt[tid] = 0;
    __syncthreads();
    int n_e = g_cursor[b];
    if (n_e > EBUF_CAP) n_e = EBUF_CAP;
    const int* eb = ebuf + b * EBUF_CAP;
    int n4 = n_e >> 2;
    for (int t = tid; t < n4; t += 512) {
        int4 v = ((const int4*)eb)[t];
        int vv[4] = { v.x, v.y, v.z, v.w };
#pragma unroll
        for (int e = 0; e < 4; ++e) {
            int dl = (vv[e] >> 16) & 255;
            int sv = vv[e] & 0xFFFF;
            int p = atomicAdd(&lcnt[dl], 1);
            if (p < SLOT_CAP) slots[(size_t)(b * 256 + dl) * SLOT_CAP + p] = (unsigned short)sv;
        }
    }
    for (int t = (n4 << 2) + tid; t < n_e; t += 512) {
        int vv = eb[t];
        int dl = (vv >> 16) & 255;
        int sv = vv & 0xFFFF;
        int p = atomicAdd(&lcnt[dl], 1);
        if (p < SLOT_CAP) slots[(size_t)(b * 256 + dl) * SLOT_CAP + p] = (unsigned short)sv;
    }
    __syncthreads();
    if (tid < 256) {
        int nid = b * 256 + tid;
        if (nid < N_NODES) cnt[nid] = lcnt[tid];
    }
}

// ---------- fused: layer1 mean-agg + relu + GEMM2 epilogue -> CD (R0-proven 119 us) ----
__global__ __launch_bounds__(256) void k_agg1f(
        const __hip_bfloat16* __restrict__ Ab, const __hip_bfloat16* __restrict__ Bh,
        const int* __restrict__ cnt, const unsigned short* __restrict__ slots,
        const float* __restrict__ Wt2f, const float* __restrict__ b2,
        float* __restrict__ CD) {
    int wave = threadIdx.x >> 6, lane = threadIdx.x & 63;
    int nid = blockIdx.x * 4 + wave;          // grid 12500 -> exact
    int half = lane >> 5;
    int c8 = (lane & 31) * 8;
    const unsigned short* row = slots + (size_t)nid * SLOT_CAP;
    int n = cnt[nid];
    if (n > SLOT_CAP) n = SLOT_CAP;
    int mid = (n + 1) >> 1;
    int beg = half ? mid : 0;
    int end = half ? n : mid;

    float s0[8], s1[8], s2[8], s3[8];
#pragma unroll
    for (int j = 0; j < 8; ++j) { s0[j] = 0.f; s1[j] = 0.f; s2[j] = 0.f; s3[j] = 0.f; }

    const __hip_bfloat16* abc = Ab + c8;
    int e = beg;
    for (; e + 4 <= end; e += 4) {
        int i0 = row[e], i1 = row[e + 1], i2 = row[e + 2], i3 = row[e + 3];
        bf16x8 v0 = *(const bf16x8*)(abc + (size_t)i0 * HID_C);
        bf16x8 v1 = *(const bf16x8*)(abc + (size_t)i1 * HID_C);
        bf16x8 v2 = *(const bf16x8*)(abc + (size_t)i2 * HID_C);
        bf16x8 v3 = *(const bf16x8*)(abc + (size_t)i3 * HID_C);
#pragma unroll
        for (int j = 0; j < 8; ++j) {
            s0[j] += b2f(v0[j]); s1[j] += b2f(v1[j]);
            s2[j] += b2f(v2[j]); s3[j] += b2f(v3[j]);
        }
    }
    for (; e < end; ++e) {
        int i0 = row[e];
        bf16x8 v0 = *(const bf16x8*)(abc + (size_t)i0 * HID_C);
#pragma unroll
        for (int j = 0; j < 8; ++j) s0[j] += b2f(v0[j]);
    }
#pragma unroll
    for (int j = 0; j < 8; ++j) s0[j] += (s1[j] + s2[j]) + s3[j];
#pragma unroll
    for (int j = 0; j < 8; ++j) s0[j] += __shfl_down(s0[j], 32, 64);

    // h = relu(mean + Bh) computed on half0, broadcast to half1
    float h[8];
    float inv = 1.f / fmaxf((float)n, 1.f);
    if (half == 0) {
        bf16x8 bb = *(const bf16x8*)(Bh + (size_t)nid * HID_C + c8);
#pragma unroll
        for (int j = 0; j < 8; ++j)
            h[j] = fmaxf(s0[j] * inv + b2f(bb[j]), 0.f);
    }
#pragma unroll
    for (int j = 0; j < 8; ++j) h[j] = __shfl(h[j], lane & 31, 64);

    // 10 dot products with W2 (fp32), reduce over 32 lanes of this half
    const float* wbase = Wt2f + (half ? 16 * 256 : 0);
    float acc[10];
#pragma unroll
    for (int j = 0; j < 10; ++j) {
        f32x4 w0 = *(const f32x4*)(wbase + j * 256 + c8);
        f32x4 w1 = *(const f32x4*)(wbase + j * 256 + c8 + 4);
        float a = h[0] * w0[0] + h[1] * w0[1] + h[2] * w0[2] + h[3] * w0[3]
                + h[4] * w1[0] + h[5] * w1[1] + h[6] * w1[2] + h[7] * w1[3];
#pragma unroll
        for (int off = 16; off > 0; off >>= 1)
            a += __shfl_down(a, off, 32);
        acc[j] = a;
    }
    if ((lane & 31) == 0) {
        float* o = CD + (size_t)nid * CD_STRIDE + half * 16;
        if (half == 0) {
#pragma unroll
            for (int j = 0; j < 10; ++j) o[j] = acc[j];
            o[10] = 0.f; o[11] = 0.f;
        } else {
#pragma unroll
            for (int j = 0; j < 10; ++j) o[j] = acc[j] + b2[j];
        }
    }
}

// ---------- layer2 aggregation + log_softmax: two nodes per wave (32 lanes each) ----------
__global__ __launch_bounds__(256) void k_agg2(
        const float* __restrict__ CD, const int* __restrict__ cnt,
        const unsigned short* __restrict__ slots, float* __restrict__ out) {
    int wave = threadIdx.x >> 6, lane = threadIdx.x & 63;
    int half = lane >> 5, sub = lane & 31;
    int nid = blockIdx.x * 8 + wave * 2 + half;   // grid 6250 -> exact
    const unsigned short* row = slots + (size_t)nid * SLOT_CAP;
    int n = cnt[nid];
    if (n > SLOT_CAP) n = SLOT_CAP;
    float s[10];
#pragma unroll
    for (int j = 0; j < 10; ++j) s[j] = 0.f;
    for (int e = sub; e < n; e += 32) {
        const float* cr = CD + (size_t)row[e] * CD_STRIDE;
        f32x4 v0 = *(const f32x4*)cr;
        f32x4 v1 = *(const f32x4*)(cr + 4);
        f32x4 v2 = *(const f32x4*)(cr + 8);   // cols 8..11 (10,11 zeroed)
#pragma unroll
        for (int j = 0; j < 4; ++j) { s[j] += v0[j]; s[4 + j] += v1[j]; }
        s[8] += v2[0]; s[9] += v2[1];
    }
#pragma unroll
    for (int j = 0; j < 10; ++j)
#pragma unroll
        for (int off = 16; off > 0; off >>= 1)
            s[j] += __shfl_down(s[j], off, 32);
    if (sub == 0) {
        float inv = 1.f / fmaxf((float)n, 1.f);
        float z[10], mx = -1e30f;
#pragma unroll
        for (int j = 0; j < 10; ++j) {
            z[j] = s[j] * inv + CD[(size_t)nid * CD_STRIDE + 16 + j];
            mx = fmaxf(mx, z[j]);
        }
        float se = 0.f;
#pragma unroll
        for (int j = 0; j < 10; ++j) se += expf(z[j] - mx);
        float lse = logf(se) + mx;
#pragma unroll
        for (int j = 0; j < 10; ++j) out[(size_t)nid * OUT_C + j] = z[j] - lse;
    }
}

extern "C" void kernel_launch(void* const* d_in, const int* in_sizes, int n_in,
                              void* d_out, int out_size, void* d_ws, size_t ws_size,
                              hipStream_t stream) {
    const float* x   = (const float*)d_in[0];
    const int*   ei  = (const int*)d_in[1];
    const float* W1l = (const float*)d_in[2];
    const float* W1r = (const float*)d_in[3];
    const float* b1  = (const float*)d_in[4];
    const float* W2l = (const float*)d_in[5];
    const float* W2r = (const float*)d_in[6];
    const float* b2  = (const float*)d_in[7];
    float* out = (float*)d_out;
    const int* src = ei;
    const int* dst = ei + N_EDGES;

    char* w = (char*)d_ws;
    size_t off = 0;
    auto alloc = [&](size_t bytes) -> void* {
        void* p = w + off;
        off = (off + bytes + 255) & ~(size_t)255;
        return p;
    };
    __hip_bfloat16* Wt   = (__hip_bfloat16*)alloc((size_t)2 * HID_C * IN_C * 2);
    float*          Wt2f = (float*)alloc((size_t)32 * 256 * 4);
    __hip_bfloat16* Ab   = (__hip_bfloat16*)alloc((size_t)N_NODES * HID_C * 2);
    __hip_bfloat16* Bh   = (__hip_bfloat16*)alloc((size_t)N_NODES * HID_C * 2);
    float* CD = (float*)alloc((size_t)N_NODES * CD_STRIDE * 4);
    int* cnt      = (int*)alloc((size_t)N_NODES * 4);
    unsigned short* slots = (unsigned short*)alloc((size_t)N_NODES * SLOT_CAP * 2);
    int* g_cursor = (int*)alloc((size_t)NBUCKET * 4);
    int* ebuf     = (int*)alloc((size_t)NBUCKET * EBUF_CAP * 4);

    (void)hipMemsetAsync(g_cursor, 0, (size_t)NBUCKET * 4, stream);

    k_prep<<<532, 256, 0, stream>>>(W1l, W1r, W2l, W2r, Wt, Wt2f);
    k_gp<<<PART_BLOCKS + 8 * 196, 256, 0, stream>>>(src, dst, g_cursor, ebuf,
                                                    x, Wt, b1, Ab, Bh);
    k_bucket<<<NBUCKET, 512, 0, stream>>>(ebuf, g_cursor, cnt, slots);
    k_agg1f<<<N_NODES / 4, 256, 0, stream>>>(Ab, Bh, cnt, slots, Wt2f, b2, CD);
    k_agg2<<<N_NODES / 8, 256, 0, stream>>>(CD, cnt, slots, out);
}

// Round 13
// 313.286 us; speedup vs baseline: 1.1229x; 1.0085x over previous
//
#include <hip/hip_runtime.h>
#include <hip/hip_bf16.h>

#define N_NODES 50000
#define N_EDGES 1600000
#define IN_C 256
#define HID_C 256
#define OUT_C 10
#define SLOT_CAP 96      // max degree; Poisson(32) max over 50K nodes ~60; 96 = 11 sigma
#define NBUCKET 196      // ceil(50000/256) dst-buckets of 256 nodes
#define EBUF_CAP 9216    // per-bucket edge capacity; mean 8163, sigma 90 -> +11.7 sigma
#define M_TILES 391      // (N_NODES+127)/128
#define PART_BLOCKS 391  // ceil((N_EDGES/4)/1024)
#define PREP_BLOCKS 532  // 512 (Wt) + 20 (Wt2f)

typedef short bf16x8 __attribute__((ext_vector_type(8)));
typedef float f32x4 __attribute__((ext_vector_type(4)));

static __device__ __forceinline__ float b2f(short v) {
    unsigned u = (unsigned)(unsigned short)v << 16;
    return __builtin_bit_cast(float, u);
}
static __device__ __forceinline__ short f2b(float f) {
    __hip_bfloat16 h = __float2bfloat16(f);
    return __builtin_bit_cast(short, h);
}
static __device__ __forceinline__ int4 pack8i(float4 a, float4 b) {
    bf16x8 o;
    o[0] = f2b(a.x); o[1] = f2b(a.y); o[2] = f2b(a.z); o[3] = f2b(a.w);
    o[4] = f2b(b.x); o[5] = f2b(b.y); o[6] = f2b(b.z); o[7] = f2b(b.w);
    return __builtin_bit_cast(int4, o);
}

// ---------- launch 1: prep (blocks 0..531) + edge partition (blocks 532..922) ----------
// Independent chains: prep writes Wt/Wt2f from weights; part buckets the edge list.
__global__ __launch_bounds__(256) void k_pp(
        const float* __restrict__ W1l, const float* __restrict__ W1r,
        const float* __restrict__ W2l, const float* __restrict__ W2r,
        __hip_bfloat16* __restrict__ Wt, float* __restrict__ Wt2f,
        const int* __restrict__ src, const int* __restrict__ dst,
        int* __restrict__ g_cursor, int* __restrict__ ebuf) {
    __shared__ int pbuf[3 * 256];
    int tid = threadIdx.x;
    int bid = blockIdx.x;

    if (bid < 512) {
        int idx = bid * 256 + tid;          // 512*256
        int n = idx >> 8, k = idx & 255;
        float v = (n < HID_C) ? W1l[k * HID_C + n] : W1r[k * HID_C + (n - HID_C)];
        Wt[idx] = __float2bfloat16(v);
        return;
    }
    if (bid < PREP_BLOCKS) {
        int idx = (bid - 512) * 256 + tid;  // 20*256
        int r = idx >> 8, k = idx & 255;
        if (r < OUT_C) Wt2f[r * 256 + k] = W2l[k * OUT_C + r];
        else           Wt2f[(16 + r - OUT_C) * 256 + k] = W2r[k * OUT_C + (r - OUT_C)];
        return;
    }

    // ---- edge partition ----
    int* hist = pbuf;
    int* base = pbuf + 256;
    int* pos  = pbuf + 512;
    int pb = bid - PREP_BLOCKS;             // 0..390
    if (tid < NBUCKET) { hist[tid] = 0; pos[tid] = 0; }
    __syncthreads();

    int4 s[4], d[4];
    bool valid[4];
#pragma unroll
    for (int q = 0; q < 4; ++q) {
        int idx = pb * 1024 + q * 256 + tid;    // int4 index, 4 edges each
        valid[q] = (idx < N_EDGES / 4);
        if (valid[q]) {
            s[q] = ((const int4*)src)[idx];
            d[q] = ((const int4*)dst)[idx];
        }
    }
#pragma unroll
    for (int q = 0; q < 4; ++q) {
        if (valid[q]) {
            atomicAdd(&hist[d[q].x >> 8], 1);
            atomicAdd(&hist[d[q].y >> 8], 1);
            atomicAdd(&hist[d[q].z >> 8], 1);
            atomicAdd(&hist[d[q].w >> 8], 1);
        }
    }
    __syncthreads();
    if (tid < NBUCKET && hist[tid] > 0)
        base[tid] = atomicAdd(&g_cursor[tid], hist[tid]);
    __syncthreads();
#pragma unroll
    for (int q = 0; q < 4; ++q) {
        if (valid[q]) {
            int ss[4] = { s[q].x, s[q].y, s[q].z, s[q].w };
            int dd[4] = { d[q].x, d[q].y, d[q].z, d[q].w };
#pragma unroll
            for (int e = 0; e < 4; ++e) {
                int b = dd[e] >> 8;
                int p = base[b] + atomicAdd(&pos[b], 1);
                if (p < EBUF_CAP)
                    ebuf[b * EBUF_CAP + p] = ss[e] | ((dd[e] & 255) << 16);
            }
        }
    }
}

// ---------- launch 2: bucket (blocks 0..195) + GEMM1 (blocks 196..1763) ----------
// bucket depends only on part (launch 1); gemm depends only on prep (launch 1).
// bucket's ~20 us hides under gemm's runtime (same mechanism as the R11 part-fusion).
// GEMM1 (R7-proven): 128x128 tile, BK=64, 4 waves (2x2 of 64x64), reg-staged prefetch,
// f32->bf16 fused into A-staging, XCD-aware flat-id swizzle, LDS C epilogue.
// (offset 196 = 4 mod 8 relabels XCDs bijectively -> panel->XCD grouping preserved)
__global__ __launch_bounds__(256) void k_gb(
        const int* __restrict__ ebuf, const int* __restrict__ g_cursor,
        int* __restrict__ cnt, unsigned short* __restrict__ slots,
        const float* __restrict__ X, const __hip_bfloat16* __restrict__ Wt,
        const float* __restrict__ b1,
        __hip_bfloat16* __restrict__ Ab, __hip_bfloat16* __restrict__ Bh) {
    __shared__ short Smem[2 * 128 * 64];   // gemm: As|Bs then C-tile; bucket: 1KB counters
    int tid = threadIdx.x;

    if (blockIdx.x < NBUCKET) {
        // ================= bucket path =================
        int* lcnt = (int*)Smem;
        int b = blockIdx.x;
        lcnt[tid] = 0;
        __syncthreads();
        int n_e = g_cursor[b];
        if (n_e > EBUF_CAP) n_e = EBUF_CAP;
        const int* eb = ebuf + b * EBUF_CAP;
        int n4 = n_e >> 2;
        for (int t = tid; t < n4; t += 256) {
            int4 v = ((const int4*)eb)[t];
            int vv[4] = { v.x, v.y, v.z, v.w };
#pragma unroll
            for (int e = 0; e < 4; ++e) {
                int dl = (vv[e] >> 16) & 255;
                int sv = vv[e] & 0xFFFF;
                int p = atomicAdd(&lcnt[dl], 1);
                if (p < SLOT_CAP) slots[(size_t)(b * 256 + dl) * SLOT_CAP + p] = (unsigned short)sv;
            }
        }
        for (int t = (n4 << 2) + tid; t < n_e; t += 256) {
            int vv = eb[t];
            int dl = (vv >> 16) & 255;
            int sv = vv & 0xFFFF;
            int p = atomicAdd(&lcnt[dl], 1);
            if (p < SLOT_CAP) slots[(size_t)(b * 256 + dl) * SLOT_CAP + p] = (unsigned short)sv;
        }
        __syncthreads();
        int nid = b * 256 + tid;
        if (nid < N_NODES) cnt[nid] = lcnt[tid];
        return;
    }

    // ================= GEMM1 path =================
    short* As = Smem;
    short* Bs = Smem + 128 * 64;
    int fid = blockIdx.x - NBUCKET;
    int xcd = fid & 7, slot = fid >> 3;
    int m_t = (slot >> 2) * 8 + xcd;
    if (m_t >= M_TILES) return;            // block-uniform guard
    int n_t = slot & 3;
    int m_base = m_t * 128;
    int n_base = n_t * 128;

    int wave = tid >> 6, lane = tid & 63;
    int r = lane & 15, quad = lane >> 4;
    int wr = wave >> 1, wc = wave & 1;

    // staging coords: thread covers 4 rows (q*32+srow) x 16B(bf16)/32B(f32) each
    int srow = tid >> 3;              // 0..31
    int kb8  = (tid & 7) * 16;        // byte offset in 128B bf16 row-slice
    int kelem = (tid & 7) * 8;        // element offset in 64-elem k-slice
    int swz  = kb8 ^ ((srow & 7) << 4);

    f32x4 acc[4][4];
#pragma unroll
    for (int i = 0; i < 4; ++i)
#pragma unroll
        for (int j = 0; j < 4; ++j) acc[i][j] = f32x4{0.f, 0.f, 0.f, 0.f};

    int4 av[4], bv[4];
    // prologue: load K-step 0 (A from f32 X, convert in regs; B already bf16)
#pragma unroll
    for (int q = 0; q < 4; ++q) {
        int grow = m_base + q * 32 + srow;
        if (grow > N_NODES - 1) grow = N_NODES - 1;
        const float* xp = X + (size_t)grow * IN_C + kelem;
        av[q] = pack8i(*(const float4*)xp, *(const float4*)(xp + 4));
        int brow = n_base + q * 32 + srow;
        bv[q] = *(const int4*)((const char*)Wt + ((size_t)brow * 512 + kb8));
    }

    for (int kk = 0; kk < 4; ++kk) {
        if (kk) __syncthreads();                 // prior reads done before overwrite
#pragma unroll
        for (int q = 0; q < 4; ++q) {
            *(int4*)((char*)As + (size_t)((q * 32 + srow) * 128 + swz)) = av[q];
            *(int4*)((char*)Bs + (size_t)((q * 32 + srow) * 128 + swz)) = bv[q];
        }
        __syncthreads();

        if (kk < 3) {                            // prefetch next K-step during compute
            int ke = (kk + 1) * 64 + kelem;
            int kbyte = (kk + 1) * 128 + kb8;
#pragma unroll
            for (int q = 0; q < 4; ++q) {
                int grow = m_base + q * 32 + srow;
                if (grow > N_NODES - 1) grow = N_NODES - 1;
                const float* xp = X + (size_t)grow * IN_C + ke;
                av[q] = pack8i(*(const float4*)xp, *(const float4*)(xp + 4));
                int brow = n_base + q * 32 + srow;
                bv[q] = *(const int4*)((const char*)Wt + ((size_t)brow * 512 + kbyte));
            }
        }

#pragma unroll
        for (int s = 0; s < 2; ++s) {
            int kfb = (s * 64 + quad * 16) ^ ((r & 7) << 4);
            bf16x8 a[4], b[4];
#pragma unroll
            for (int i = 0; i < 4; ++i)
                a[i] = *(const bf16x8*)((const char*)As + (size_t)((wr * 64 + i * 16 + r) * 128) + kfb);
#pragma unroll
            for (int j = 0; j < 4; ++j)
                b[j] = *(const bf16x8*)((const char*)Bs + (size_t)((wc * 64 + j * 16 + r) * 128) + kfb);
#pragma unroll
            for (int i = 0; i < 4; ++i)
#pragma unroll
                for (int j = 0; j < 4; ++j)
                    acc[i][j] = __builtin_amdgcn_mfma_f32_16x16x32_bf16(a[i], b[j], acc[i][j], 0, 0, 0);
        }
    }

    // ---- C epilogue via LDS: scatter acc (bf16) into 128x128 tile, then coalesced copy ----
    __syncthreads();                      // all waves done reading As/Bs
    short* Cs = Smem;                     // 128 rows x 128 cols bf16, 256B rows, swizzled
    bool left = (n_base < HID_C);         // block-uniform (n_t 0,1 -> Ab; 2,3 -> Bh)
#pragma unroll
    for (int j = 0; j < 4; ++j) {
        int coll = wc * 64 + 16 * j + r;  // local col 0..127
        float bias = left ? 0.f : b1[n_base + coll - HID_C];
#pragma unroll
        for (int i = 0; i < 4; ++i) {
#pragma unroll
            for (int ii = 0; ii < 4; ++ii) {
                int rowl = wr * 64 + 16 * i + quad * 4 + ii;
                int byteoff = (coll * 2) ^ ((rowl & 7) << 4);   // 16B-granular XOR swizzle
                *(short*)((char*)Cs + rowl * 256 + byteoff) = f2b(acc[i][j][ii] + bias);
            }
        }
    }
    __syncthreads();

    // copy-out: 16 lanes cover one 256B row (16B each) -> fully-coalesced lines
    int rrow = tid >> 4;                  // 0..15
    int cchunk = (tid & 15) * 16;         // byte offset in row
    size_t colbyte = left ? (size_t)(n_base * 2) : (size_t)((n_base - HID_C) * 2);
    char* outp = left ? (char*)Ab : (char*)Bh;
    for (int rb = 0; rb < 128; rb += 16) {
        int rowl = rb + rrow;
        int4 v = *(const int4*)((const char*)Cs + rowl * 256 + (cchunk ^ ((rowl & 7) << 4)));
        int grow = m_base + rowl;
        if (grow < N_NODES)
            *(int4*)(outp + (size_t)grow * 512 + colbyte + cchunk) = v;
    }
}

// ---------- fused: layer1 mean-agg + relu + GEMM2 epilogue -> CDl/CDr ----------
// CDl [node][12] f32 (48B rows, 2.4 MB -> XCD-L2-resident for agg2's random gather);
// CDr [node][12] f32, read once sequentially by agg2.
__global__ __launch_bounds__(256) void k_agg1f(
        const __hip_bfloat16* __restrict__ Ab, const __hip_bfloat16* __restrict__ Bh,
        const int* __restrict__ cnt, const unsigned short* __restrict__ slots,
        const float* __restrict__ Wt2f, const float* __restrict__ b2,
        float* __restrict__ CDl, float* __restrict__ CDr) {
    int wave = threadIdx.x >> 6, lane = threadIdx.x & 63;
    int nid = blockIdx.x * 4 + wave;          // grid 12500 -> exact
    int half = lane >> 5;
    int c8 = (lane & 31) * 8;
    const unsigned short* row = slots + (size_t)nid * SLOT_CAP;
    int n = cnt[nid];
    if (n > SLOT_CAP) n = SLOT_CAP;
    int mid = (n + 1) >> 1;
    int beg = half ? mid : 0;
    int end = half ? n : mid;

    float s0[8], s1[8], s2[8], s3[8];
#pragma unroll
    for (int j = 0; j < 8; ++j) { s0[j] = 0.f; s1[j] = 0.f; s2[j] = 0.f; s3[j] = 0.f; }

    const __hip_bfloat16* abc = Ab + c8;
    int e = beg;
    for (; e + 4 <= end; e += 4) {
        int i0 = row[e], i1 = row[e + 1], i2 = row[e + 2], i3 = row[e + 3];
        bf16x8 v0 = *(const bf16x8*)(abc + (size_t)i0 * HID_C);
        bf16x8 v1 = *(const bf16x8*)(abc + (size_t)i1 * HID_C);
        bf16x8 v2 = *(const bf16x8*)(abc + (size_t)i2 * HID_C);
        bf16x8 v3 = *(const bf16x8*)(abc + (size_t)i3 * HID_C);
#pragma unroll
        for (int j = 0; j < 8; ++j) {
            s0[j] += b2f(v0[j]); s1[j] += b2f(v1[j]);
            s2[j] += b2f(v2[j]); s3[j] += b2f(v3[j]);
        }
    }
    for (; e < end; ++e) {
        int i0 = row[e];
        bf16x8 v0 = *(const bf16x8*)(abc + (size_t)i0 * HID_C);
#pragma unroll
        for (int j = 0; j < 8; ++j) s0[j] += b2f(v0[j]);
    }
#pragma unroll
    for (int j = 0; j < 8; ++j) s0[j] += (s1[j] + s2[j]) + s3[j];
#pragma unroll
    for (int j = 0; j < 8; ++j) s0[j] += __shfl_down(s0[j], 32, 64);

    // h = relu(mean + Bh) computed on half0, broadcast to half1
    float h[8];
    float inv = 1.f / fmaxf((float)n, 1.f);
    if (half == 0) {
        bf16x8 bb = *(const bf16x8*)(Bh + (size_t)nid * HID_C + c8);
#pragma unroll
        for (int j = 0; j < 8; ++j)
            h[j] = fmaxf(s0[j] * inv + b2f(bb[j]), 0.f);
    }
#pragma unroll
    for (int j = 0; j < 8; ++j) h[j] = __shfl(h[j], lane & 31, 64);

    // 10 dot products with W2 (fp32), reduce over 32 lanes of this half
    const float* wbase = Wt2f + (half ? 16 * 256 : 0);
    float acc[10];
#pragma unroll
    for (int j = 0; j < 10; ++j) {
        f32x4 w0 = *(const f32x4*)(wbase + j * 256 + c8);
        f32x4 w1 = *(const f32x4*)(wbase + j * 256 + c8 + 4);
        float a = h[0] * w0[0] + h[1] * w0[1] + h[2] * w0[2] + h[3] * w0[3]
                + h[4] * w1[0] + h[5] * w1[1] + h[6] * w1[2] + h[7] * w1[3];
#pragma unroll
        for (int off = 16; off > 0; off >>= 1)
            a += __shfl_down(a, off, 32);
        acc[j] = a;
    }
    if ((lane & 31) == 0) {
        if (half == 0) {
            float* o = CDl + (size_t)nid * 12;
#pragma unroll
            for (int j = 0; j < 10; ++j) o[j] = acc[j];
            o[10] = 0.f; o[11] = 0.f;
        } else {
            float* o = CDr + (size_t)nid * 12;
#pragma unroll
            for (int j = 0; j < 10; ++j) o[j] = acc[j] + b2[j];
        }
    }
}

// ---------- layer2 aggregation + log_softmax: two nodes per wave (32 lanes each) ----------
__global__ __launch_bounds__(256) void k_agg2(
        const float* __restrict__ CDl, const float* __restrict__ CDr,
        const int* __restrict__ cnt, const unsigned short* __restrict__ slots,
        float* __restrict__ out) {
    int wave = threadIdx.x >> 6, lane = threadIdx.x & 63;
    int half = lane >> 5, sub = lane & 31;
    int nid = blockIdx.x * 8 + wave * 2 + half;   // grid 6250 -> exact
    const unsigned short* row = slots + (size_t)nid * SLOT_CAP;
    int n = cnt[nid];
    if (n > SLOT_CAP) n = SLOT_CAP;
    float s[10];
#pragma unroll
    for (int j = 0; j < 10; ++j) s[j] = 0.f;
    for (int e = sub; e < n; e += 32) {
        const float* cr = CDl + (size_t)row[e] * 12;   // 48B row, L2-resident slab
        f32x4 v0 = *(const f32x4*)cr;
        f32x4 v1 = *(const f32x4*)(cr + 4);
        f32x4 v2 = *(const f32x4*)(cr + 8);   // cols 8..11 (10,11 zeroed)
#pragma unroll
        for (int j = 0; j < 4; ++j) { s[j] += v0[j]; s[4 + j] += v1[j]; }
        s[8] += v2[0]; s[9] += v2[1];
    }
#pragma unroll
    for (int j = 0; j < 10; ++j)
#pragma unroll
        for (int off = 16; off > 0; off >>= 1)
            s[j] += __shfl_down(s[j], off, 32);
    if (sub == 0) {
        float inv = 1.f / fmaxf((float)n, 1.f);
        const float* rr = CDr + (size_t)nid * 12;
        float z[10], mx = -1e30f;
#pragma unroll
        for (int j = 0; j < 10; ++j) {
            z[j] = s[j] * inv + rr[j];
            mx = fmaxf(mx, z[j]);
        }
        float se = 0.f;
#pragma unroll
        for (int j = 0; j < 10; ++j) se += expf(z[j] - mx);
        float lse = logf(se) + mx;
#pragma unroll
        for (int j = 0; j < 10; ++j) out[(size_t)nid * OUT_C + j] = z[j] - lse;
    }
}

extern "C" void kernel_launch(void* const* d_in, const int* in_sizes, int n_in,
                              void* d_out, int out_size, void* d_ws, size_t ws_size,
                              hipStream_t stream) {
    const float* x   = (const float*)d_in[0];
    const int*   ei  = (const int*)d_in[1];
    const float* W1l = (const float*)d_in[2];
    const float* W1r = (const float*)d_in[3];
    const float* b1  = (const float*)d_in[4];
    const float* W2l = (const float*)d_in[5];
    const float* W2r = (const float*)d_in[6];
    const float* b2  = (const float*)d_in[7];
    float* out = (float*)d_out;
    const int* src = ei;
    const int* dst = ei + N_EDGES;

    char* w = (char*)d_ws;
    size_t off = 0;
    auto alloc = [&](size_t bytes) -> void* {
        void* p = w + off;
        off = (off + bytes + 255) & ~(size_t)255;
        return p;
    };
    __hip_bfloat16* Wt   = (__hip_bfloat16*)alloc((size_t)2 * HID_C * IN_C * 2);
    float*          Wt2f = (float*)alloc((size_t)32 * 256 * 4);
    __hip_bfloat16* Ab   = (__hip_bfloat16*)alloc((size_t)N_NODES * HID_C * 2);
    __hip_bfloat16* Bh   = (__hip_bfloat16*)alloc((size_t)N_NODES * HID_C * 2);
    float* CDl = (float*)alloc((size_t)N_NODES * 12 * 4);
    float* CDr = (float*)alloc((size_t)N_NODES * 12 * 4);
    int* cnt      = (int*)alloc((size_t)N_NODES * 4);
    unsigned short* slots = (unsigned short*)alloc((size_t)N_NODES * SLOT_CAP * 2);
    int* g_cursor = (int*)alloc((size_t)NBUCKET * 4);
    int* ebuf     = (int*)alloc((size_t)NBUCKET * EBUF_CAP * 4);

    (void)hipMemsetAsync(g_cursor, 0, (size_t)NBUCKET * 4, stream);

    k_pp<<<PREP_BLOCKS + PART_BLOCKS, 256, 0, stream>>>(W1l, W1r, W2l, W2r, Wt, Wt2f,
                                                        src, dst, g_cursor, ebuf);
    k_gb<<<NBUCKET + 8 * 196, 256, 0, stream>>>(ebuf, g_cursor, cnt, slots,
                                                x, Wt, b1, Ab, Bh);
    k_agg1f<<<N_NODES / 4, 256, 0, stream>>>(Ab, Bh, cnt, slots, Wt2f, b2, CDl, CDr);
    k_agg2<<<N_NODES / 8, 256, 0, stream>>>(CDl, CDr, cnt, slots, out);
}